// Round 6
// baseline (322.707 us; speedup 1.0000x reference)
//
#include <hip/hip_runtime.h>

#define V 50000
#define E_DIM 256
#define H_DIM 512
#define H2 1024
#define G3 1536
#define BSZ 64
#define SEQ 200
#define KX 1280
#define MROWS 12800
#define NBLK_WO 782  // ceil(50000/64)

// ws offsets (float units)
#define XBF_OFF   0        // 64*1280 bf16
#define H0_OFF    40960    // 64*512 f32
#define H0BF_OFF  73728    // 64*512 bf16
#define GI_OFF    90112    // 64*1536 f32
#define GH_OFF    188416   // 64*1536 f32
#define STBF_OFF  286720   // 64*512 bf16
#define WCBF_OFF  303104   // 512*1024 bf16
#define SC_OFF    565248   // 2*12800 f32 (n-half partials)
#define REDG_OFF  590848   // 64*782*2 f32
#define RED_OFF   690944   // 64*2 f32

// d_out layout (floats)
#define OUT_STATE 3200000
#define OUT_W     3232768

typedef __attribute__((ext_vector_type(8))) short bf16x8;
typedef __attribute__((ext_vector_type(4))) float f32x4;

__device__ __forceinline__ float sigmf(float x) { return 1.f / (1.f + __expf(-x)); }

__device__ __forceinline__ ushort f2bf(float f) {
  uint u = __float_as_uint(f);
  uint r = (u + 0x7FFFu + ((u >> 16) & 1u)) >> 16;
  return (ushort)r;
}

__device__ __forceinline__ float tanhfast(float x) {
  float xc = fminf(15.f, fmaxf(-15.f, x));
  float e = __expf(2.f * xc);
  return (e - 1.f) * __builtin_amdgcn_rcpf(e + 1.f);
}

// packed f32->bf16 (RNE), 4 instructions for 8 elements
__device__ __forceinline__ bf16x8 cvt8(float4 a, float4 b) {
  union { bf16x8 v; uint u[4]; } r;
  asm("v_cvt_pk_bf16_f32 %0, %1, %2" : "=v"(r.u[0]) : "v"(a.x), "v"(a.y));
  asm("v_cvt_pk_bf16_f32 %0, %1, %2" : "=v"(r.u[1]) : "v"(a.z), "v"(a.w));
  asm("v_cvt_pk_bf16_f32 %0, %1, %2" : "=v"(r.u[2]) : "v"(b.x), "v"(b.y));
  asm("v_cvt_pk_bf16_f32 %0, %1, %2" : "=v"(r.u[3]) : "v"(b.z), "v"(b.w));
  return r.v;
}

// ---------------- kprep: Wc f32->bf16 (blocks 0..511) + build x_bf/h0 (blocks 512..575)
__global__ void kprep(const float* __restrict__ Wc_W, ushort* __restrict__ Wc_bf,
                      const int* __restrict__ input_idx, const float* __restrict__ encoded,
                      const float* __restrict__ prev_state, const float* __restrict__ weighted,
                      const int* __restrict__ order_p, const float* __restrict__ embed_W,
                      const float* __restrict__ Ws_W, const float* __restrict__ Ws_b,
                      ushort* __restrict__ x_bf, float* __restrict__ h0,
                      ushort* __restrict__ h0_bf) {
  int bid = blockIdx.x, tid = threadIdx.x;
  if (bid < 512) {
    int i = bid * 256 + tid;
    float4 v = ((const float4*)Wc_W)[i];
    ushort4 o;
    o.x = f2bf(v.x); o.y = f2bf(v.y); o.z = f2bf(v.z); o.w = f2bf(v.w);
    ((ushort4*)Wc_bf)[i] = o;
    return;
  }
  int b = bid - 512;
  int order = order_p[0];
  int idx = input_idx[b];
  x_bf[b * KX + tid] = f2bf(embed_W[(size_t)idx * E_DIM + tid]);
  if (order != 0) {
    for (int j = tid; j < H2; j += 256) x_bf[b * KX + E_DIM + j] = f2bf(weighted[b * H2 + j]);
    for (int j = tid; j < H_DIM; j += 256) {
      float v = prev_state[b * H_DIM + j];
      h0[b * H_DIM + j] = v;
      h0_bf[b * H_DIM + j] = f2bf(v);
    }
  } else {
    for (int j = tid; j < H2; j += 256) x_bf[b * KX + E_DIM + j] = 0;
    const float* er = encoded + ((size_t)b * SEQ + 1) * H2;
    for (int j = tid; j < H_DIM; j += 256) {
      float acc = Ws_b[j];
      const float* wr = Ws_W + (size_t)j * H2;
      for (int k = 0; k < H2; ++k) acc = fmaf(er[k], wr[k], acc);
      h0[b * H_DIM + j] = acc;
      h0_bf[b * H_DIM + j] = f2bf(acc);
    }
  }
}

// ---------------- shared GEMM body: out[m][n] = A[m][:] . W[n][:] + bias[n]
// W loads (HBM stream) go through a 3-deep register pipeline in a ROLLED loop
// (unroll 1): loads live across the backedge -> compiler must keep buffers and
// emit counted vmcnt. kdim must have kdim/32 % 3 == 1 (512->16, 1280->40).
template <bool EPI>
__device__ __forceinline__ void gemm_body(const ushort* __restrict__ Abf,
                                          const float* __restrict__ W,
                                          const float* __restrict__ bias,
                                          float* __restrict__ out, int N, int kdim,
                                          float* __restrict__ redg, int bid) {
  int tid = threadIdx.x;
  int lane = tid & 63, wv = tid >> 6;
  int l15 = lane & 15, lg = lane >> 4;
  int n0 = (bid * 4 + wv) * 16;
  int col = n0 + l15;
  bool valid = col < N;
  int colc = valid ? col : N - 1;
  const int KS = kdim / 32;
  f32x4 acc[4];
#pragma unroll
  for (int mt = 0; mt < 4; ++mt) acc[mt] = (f32x4){0.f, 0.f, 0.f, 0.f};
  const float* wrow = W + (size_t)colc * kdim + lg * 8;
  const ushort* arow = Abf + (size_t)l15 * kdim + lg * 8;

  float4 wF[3][2];
#define WLD(bu, kcv)                                                          \
  do {                                                                        \
    int kk = ((kcv) < KS ? (kcv) : KS - 1) * 32;                              \
    wF[bu][0] = *(const float4*)(wrow + kk);                                  \
    wF[bu][1] = *(const float4*)(wrow + kk + 4);                              \
  } while (0)
#define WST(bu, kc)                                                           \
  do {                                                                        \
    bf16x8 bf = cvt8(wF[bu][0], wF[bu][1]);                                   \
    int kk = (kc) * 32;                                                       \
    _Pragma("unroll") for (int mt = 0; mt < 4; ++mt) {                        \
      bf16x8 af = *(const bf16x8*)(arow + (size_t)mt * 16 * kdim + kk);       \
      acc[mt] = __builtin_amdgcn_mfma_f32_16x16x32_bf16(af, bf, acc[mt], 0, 0, 0); \
    }                                                                         \
  } while (0)

  WLD(0, 0); WLD(1, 1); WLD(2, 2);
  const int nfull = KS / 3;
#pragma unroll 1
  for (int i = 0; i < nfull; ++i) {
    int kc = i * 3;
    WST(0, kc);     WLD(0, kc + 3);
    WST(1, kc + 1); WLD(1, kc + 4);
    WST(2, kc + 2); WLD(2, kc + 5);
  }
  WST(0, KS - 1);  // KS % 3 == 1 tail
#undef WLD
#undef WST

  float bv = bias[colc];
  if (valid) {
#pragma unroll
    for (int mt = 0; mt < 4; ++mt)
#pragma unroll
      for (int r = 0; r < 4; ++r)
        out[(size_t)(mt * 16 + lg * 4 + r) * N + col] = acc[mt][r] + bv;
  }
  if constexpr (EPI) {
    __shared__ float sm[4][64], ss[4][64];
#pragma unroll
    for (int mt = 0; mt < 4; ++mt)
#pragma unroll
      for (int r = 0; r < 4; ++r) {
        float v = valid ? acc[mt][r] + bv : -1e30f;
        float mx = v;
#pragma unroll
        for (int off = 1; off < 16; off <<= 1) mx = fmaxf(mx, __shfl_xor(mx, off, 64));
        float e = valid ? __expf(v - mx) : 0.f;
#pragma unroll
        for (int off = 1; off < 16; off <<= 1) e += __shfl_xor(e, off, 64);
        if (l15 == 0) {
          sm[wv][mt * 16 + lg * 4 + r] = mx;
          ss[wv][mt * 16 + lg * 4 + r] = e;
        }
      }
    __syncthreads();
    if (tid < 64) {
      float M = -1e30f, S = 0.f;
#pragma unroll
      for (int w = 0; w < 4; ++w) {
        float m2 = sm[w][tid], s2 = ss[w][tid];
        float mn = fmaxf(M, m2);
        S = S * __expf(M - mn) + s2 * __expf(m2 - mn);
        M = mn;
      }
      redg[((size_t)tid * NBLK_WO + bid) * 2] = M;
      redg[((size_t)tid * NBLK_WO + bid) * 2 + 1] = S;
    }
  }
}

// gi/gh fused (grid.y selects)
__global__ __launch_bounds__(256) void mfma_gates(const ushort* __restrict__ x_bf,
                                                  const float* __restrict__ Wih,
                                                  const float* __restrict__ bih,
                                                  const ushort* __restrict__ h0_bf,
                                                  const float* __restrict__ Whh,
                                                  const float* __restrict__ bhh,
                                                  float* __restrict__ gi, float* __restrict__ gh) {
  if (blockIdx.y == 0)
    gemm_body<false>(x_bf, Wih, bih, gi, G3, KX, nullptr, blockIdx.x);
  else
    gemm_body<false>(h0_bf, Whh, bhh, gh, G3, H_DIM, nullptr, blockIdx.x);
}

// Wo GEMM + softmax partials
__global__ __launch_bounds__(256) void mfma_wo(const ushort* __restrict__ state_bf,
                                               const float* __restrict__ Wo_W,
                                               const float* __restrict__ Wo_b,
                                               float* __restrict__ out,
                                               float* __restrict__ redg) {
  gemm_body<true>(state_bf, Wo_W, Wo_b, out, V, H_DIM, redg, blockIdx.x);
}

// ---------------- K2: GRU cell -> state f32 (d_out) + bf16 (ws)
__global__ void k2_gru(const float* __restrict__ gi, const float* __restrict__ gh,
                       const float* __restrict__ h0, float* __restrict__ state_out,
                       ushort* __restrict__ state_bf) {
  int b = blockIdx.x, j = threadIdx.x;  // block = 512
  float ir = gi[b * G3 + j], iz = gi[b * G3 + H_DIM + j], inn = gi[b * G3 + 2 * H_DIM + j];
  float hr = gh[b * G3 + j], hz = gh[b * G3 + H_DIM + j], hn = gh[b * G3 + 2 * H_DIM + j];
  float r = sigmf(ir + hr);
  float z = sigmf(iz + hz);
  float n = tanhf(inn + r * hn);
  float st = (1.f - z) * n + z * h0[b * H_DIM + j];
  state_out[b * H_DIM + j] = st;
  state_bf[b * H_DIM + j] = f2bf(st);
}

// ---------------- K4 v5: score_c partials. Barrier-free main loop, LDS-free,
// 3-deep register pipeline in a ROLLED loop (rotation written out as 3 sub-steps).
// 400 blocks = 200 m-tiles x 2 n-halves; 8 waves = 2 mg x 4 ng; wave = 2 mf x 4 nf.
// Epilogue: tanh*state dot, shfl reduce, LDS reduce across ng -> scpart[nhalf].
__global__ __launch_bounds__(512) void k4_mfma5(const float* __restrict__ encoded,
                                                const ushort* __restrict__ Wc_bf,
                                                const float* __restrict__ Wc_b,
                                                const float* __restrict__ state,
                                                float* __restrict__ scpart) {
  int tid = threadIdx.x, lane = tid & 63, wv = tid >> 6;
  int l15 = lane & 15, lg = lane >> 4;
  int bid = blockIdx.x;
  int mtile = bid >> 1, nhalf = bid & 1;
  int mg = wv >> 2, ng = wv & 3;
  int mbase = mtile * 64 + mg * 32;
  int nbase = nhalf * 256 + ng * 64;
  const float* aptr = encoded + (size_t)(mbase + l15) * H2 + lg * 8;
  const ushort* bptr = Wc_bf + (size_t)(nbase + l15) * H2 + lg * 8;

  f32x4 acc[2][4];
#pragma unroll
  for (int mf = 0; mf < 2; ++mf)
#pragma unroll
    for (int nf = 0; nf < 4; ++nf) acc[mf][nf] = (f32x4){0.f, 0.f, 0.f, 0.f};

  float4 aF[3][2][2];
  bf16x8 bF[3][4];

#define LOADK(bu, kcv)                                                   \
  do {                                                                   \
    int kk = ((kcv) < 32 ? (kcv) : 31) * 32;                             \
    aF[bu][0][0] = *(const float4*)(aptr + kk);                          \
    aF[bu][0][1] = *(const float4*)(aptr + kk + 4);                      \
    aF[bu][1][0] = *(const float4*)(aptr + 16 * H2 + kk);                \
    aF[bu][1][1] = *(const float4*)(aptr + 16 * H2 + kk + 4);            \
    bF[bu][0] = *(const bf16x8*)(bptr + kk);                             \
    bF[bu][1] = *(const bf16x8*)(bptr + 16 * H2 + kk);                   \
    bF[bu][2] = *(const bf16x8*)(bptr + 32 * H2 + kk);                   \
    bF[bu][3] = *(const bf16x8*)(bptr + 48 * H2 + kk);                   \
  } while (0)
#define MSTEP(bu)                                                                           \
  do {                                                                                      \
    bf16x8 af0 = cvt8(aF[bu][0][0], aF[bu][0][1]);                                          \
    bf16x8 af1 = cvt8(aF[bu][1][0], aF[bu][1][1]);                                          \
    acc[0][0] = __builtin_amdgcn_mfma_f32_16x16x32_bf16(af0, bF[bu][0], acc[0][0], 0, 0, 0); \
    acc[1][0] = __builtin_amdgcn_mfma_f32_16x16x32_bf16(af1, bF[bu][0], acc[1][0], 0, 0, 0); \
    acc[0][1] = __builtin_amdgcn_mfma_f32_16x16x32_bf16(af0, bF[bu][1], acc[0][1], 0, 0, 0); \
    acc[1][1] = __builtin_amdgcn_mfma_f32_16x16x32_bf16(af1, bF[bu][1], acc[1][1], 0, 0, 0); \
    acc[0][2] = __builtin_amdgcn_mfma_f32_16x16x32_bf16(af0, bF[bu][2], acc[0][2], 0, 0, 0); \
    acc[1][2] = __builtin_amdgcn_mfma_f32_16x16x32_bf16(af1, bF[bu][2], acc[1][2], 0, 0, 0); \
    acc[0][3] = __builtin_amdgcn_mfma_f32_16x16x32_bf16(af0, bF[bu][3], acc[0][3], 0, 0, 0); \
    acc[1][3] = __builtin_amdgcn_mfma_f32_16x16x32_bf16(af1, bF[bu][3], acc[1][3], 0, 0, 0); \
  } while (0)

  LOADK(0, 0); LOADK(1, 1); LOADK(2, 2);
#pragma unroll 1
  for (int i = 0; i < 10; ++i) {
    int kc = i * 3;
    MSTEP(0); LOADK(0, kc + 3);
    MSTEP(1); LOADK(1, kc + 4);
    MSTEP(2); LOADK(2, kc + 5);
  }
  MSTEP(0);  // k=30
  MSTEP(1);  // k=31
#undef LOADK
#undef MSTEP

  // epilogue: tanh(+bias)*state, reduce over cols (shfl over l15), then LDS over ng
  float pv[2][4];
#pragma unroll
  for (int mf = 0; mf < 2; ++mf)
#pragma unroll
    for (int r = 0; r < 4; ++r) pv[mf][r] = 0.f;
#pragma unroll
  for (int nf = 0; nf < 4; ++nf) {
    int n = nbase + nf * 16 + l15;
    float bias = Wc_b[n];
#pragma unroll
    for (int mf = 0; mf < 2; ++mf) {
      int mrow = mbase + mf * 16 + lg * 4;
#pragma unroll
      for (int r = 0; r < 4; ++r) {
        int b = (mrow + r) / SEQ;
        pv[mf][r] += tanhfast(acc[mf][nf][r] + bias) * state[b * H_DIM + n];
      }
    }
  }
#pragma unroll
  for (int off = 1; off < 16; off <<= 1)
#pragma unroll
    for (int mf = 0; mf < 2; ++mf)
#pragma unroll
      for (int r = 0; r < 4; ++r) pv[mf][r] += __shfl_xor(pv[mf][r], off, 64);

  __shared__ float sred[2][4][32];
  if (l15 == 0) {
#pragma unroll
    for (int mf = 0; mf < 2; ++mf)
#pragma unroll
      for (int r = 0; r < 4; ++r) sred[mg][ng][mf * 16 + lg * 4 + r] = pv[mf][r];
  }
  __syncthreads();
  if (tid < 64) {
    int mgx = tid >> 5, rr = tid & 31;
    float s = sred[mgx][0][rr] + sred[mgx][1][rr] + sred[mgx][2][rr] + sred[mgx][3][rr];
    scpart[(size_t)nhalf * MROWS + mtile * 64 + tid] = s;
  }
}

// ---------------- kred: combine redg partials + score_c tail -> red[b] = (max, sum)
__global__ void kred(const float* __restrict__ redg, const float* __restrict__ scpart,
                     const int* __restrict__ eidx, float* __restrict__ red) {
  int b = blockIdx.x, tid = threadIdx.x;
  float m = -1e30f, s = 0.f;
  for (int i = tid; i < NBLK_WO; i += 256) {
    float m2 = redg[((size_t)b * NBLK_WO + i) * 2];
    float s2 = redg[((size_t)b * NBLK_WO + i) * 2 + 1];
    float mn = fmaxf(m, m2);
    s = s * __expf(m - mn) + s2 * __expf(m2 - mn);
    m = mn;
  }
  for (int i = tid; i < SEQ; i += 256) {
    int idx = b * SEQ + i;
    int ei = eidx[idx];
    float scv = scpart[idx] + scpart[MROWS + idx];
    float sc = tanhf(scv + (ei == 0 ? -1000.f : 0.f));
    float mn = fmaxf(m, sc);
    s = s * __expf(m - mn) + __expf(sc - mn);
    m = mn;
  }
  __shared__ float ms[256], ssh[256];
  ms[tid] = m; ssh[tid] = s;
  __syncthreads();
  for (int off = 128; off > 0; off >>= 1) {
    if (tid < off) {
      float m2 = ms[tid + off], s2 = ssh[tid + off];
      float mn = fmaxf(ms[tid], m2);
      ssh[tid] = ssh[tid] * __expf(ms[tid] - mn) + s2 * __expf(m2 - mn);
      ms[tid] = mn;
    }
    __syncthreads();
  }
  if (tid == 0) {
    red[b * 2] = ms[0];
    red[b * 2 + 1] = ssh[0];
  }
}

// ---------------- K7: score_g -> prob_g in place
__global__ void k7_probs(float* __restrict__ sg, const float* __restrict__ red) {
  int i = blockIdx.x * 256 + threadIdx.x;
  int b = i / 12500;
  float mm = red[b * 2], rd = 1.f / red[b * 2 + 1];
  float4* p = (float4*)sg;
  float4 v = p[i];
  v.x = __expf(v.x - mm) * rd;
  v.y = __expf(v.y - mm) * rd;
  v.z = __expf(v.z - mm) * rd;
  v.w = __expf(v.w - mm) * rd;
  p[i] = v;
}

// ---------------- K8: prob_c scatter-add + match-attn weighted sum
__global__ void k8_copy(const float* __restrict__ scpart, const int* __restrict__ eidx,
                        const int* __restrict__ input_idx, const float* __restrict__ red,
                        const float* __restrict__ encoded, float* __restrict__ out,
                        float* __restrict__ wout) {
  int b = blockIdx.x, tid = threadIdx.x;
  __shared__ float att_s[SEQ];
  __shared__ int cnt_s[256];
  float mm = red[b * 2], rd = 1.f / red[b * 2 + 1];
  int inp = input_idx[b];
  int cnt = 0;
  for (int s = tid; s < SEQ; s += 256) {
    int idx = b * SEQ + s;
    int ei = eidx[idx];
    float scv = scpart[idx] + scpart[MROWS + idx];
    float sc = tanhf(scv + (ei == 0 ? -1000.f : 0.f));
    float p = __expf(sc - mm) * rd;
    bool mt = (ei == inp);
    att_s[s] = mt ? p : 0.f;
    cnt += mt ? 1 : 0;
    atomicAdd(&out[(size_t)b * V + ei], p);
  }
  cnt_s[tid] = cnt;
  __syncthreads();
  for (int off = 128; off > 0; off >>= 1) {
    if (tid < off) cnt_s[tid] += cnt_s[tid + off];
    __syncthreads();
  }
  int c = cnt_s[0];
  float scale = (c > 1) ? 1.f / (float)c : 1.f;
  float w0 = 0, w1 = 0, w2 = 0, w3 = 0;
  for (int s = 0; s < SEQ; ++s) {
    float a = att_s[s];
    if (a != 0.f) {
      const float* er = encoded + ((size_t)b * SEQ + s) * H2;
      w0 += a * er[tid];
      w1 += a * er[tid + 256];
      w2 += a * er[tid + 512];
      w3 += a * er[tid + 768];
    }
  }
  wout[b * H2 + tid] = w0 * scale;
  wout[b * H2 + tid + 256] = w1 * scale;
  wout[b * H2 + tid + 512] = w2 * scale;
  wout[b * H2 + tid + 768] = w3 * scale;
}

extern "C" void kernel_launch(void* const* d_in, const int* in_sizes, int n_in,
                              void* d_out, int out_size, void* d_ws, size_t ws_size,
                              hipStream_t stream) {
  const int* input_idx = (const int*)d_in[0];
  const float* encoded = (const float*)d_in[1];
  const int* encoded_idx = (const int*)d_in[2];
  const float* prev_state = (const float*)d_in[3];
  const float* weighted = (const float*)d_in[4];
  const int* order_p = (const int*)d_in[5];
  const float* embed_W = (const float*)d_in[6];
  const float* Wih = (const float*)d_in[7];
  const float* Whh = (const float*)d_in[8];
  const float* bih = (const float*)d_in[9];
  const float* bhh = (const float*)d_in[10];
  const float* Ws_W = (const float*)d_in[11];
  const float* Ws_b = (const float*)d_in[12];
  const float* Wo_W = (const float*)d_in[13];
  const float* Wo_b = (const float*)d_in[14];
  const float* Wc_W = (const float*)d_in[15];
  const float* Wc_b = (const float*)d_in[16];

  float* ws = (float*)d_ws;
  float* out = (float*)d_out;
  ushort* x_bf = (ushort*)(ws + XBF_OFF);
  float* h0 = ws + H0_OFF;
  ushort* h0_bf = (ushort*)(ws + H0BF_OFF);
  float* gi = ws + GI_OFF;
  float* gh = ws + GH_OFF;
  ushort* state_bf = (ushort*)(ws + STBF_OFF);
  ushort* Wc_bf = (ushort*)(ws + WCBF_OFF);
  float* scpart = ws + SC_OFF;
  float* redg = ws + REDG_OFF;
  float* red = ws + RED_OFF;
  float* state = out + OUT_STATE;
  float* wout = out + OUT_W;

  kprep<<<576, 256, 0, stream>>>(Wc_W, Wc_bf, input_idx, encoded, prev_state, weighted,
                                 order_p, embed_W, Ws_W, Ws_b, x_bf, h0, h0_bf);
  mfma_gates<<<dim3(24, 2), 256, 0, stream>>>(x_bf, Wih, bih, h0_bf, Whh, bhh, gi, gh);
  k2_gru<<<64, 512, 0, stream>>>(gi, gh, h0, state, state_bf);
  mfma_wo<<<NBLK_WO, 256, 0, stream>>>(state_bf, Wo_W, Wo_b, out, redg);
  k4_mfma5<<<400, 512, 0, stream>>>(encoded, Wc_bf, Wc_b, state, scpart);
  kred<<<64, 256, 0, stream>>>(redg, scpart, encoded_idx, red);
  k7_probs<<<3125, 256, 0, stream>>>(out, red);
  k8_copy<<<64, 256, 0, stream>>>(scpart, encoded_idx, input_idx, red, encoded, out, wout);
}

// Round 7
// 152.443 us; speedup vs baseline: 2.1169x; 2.1169x over previous
//
#include <hip/hip_runtime.h>

#define V 50000
#define E_DIM 256
#define H_DIM 512
#define H2 1024
#define G3 1536
#define BSZ 64
#define SEQ 200
#define KX 1280
#define MROWS 12800
#define NBLK_WO 391  // ceil(50000/128)

// ws offsets (float units)
#define XBF_OFF   0        // 64*1280 bf16
#define H0_OFF    40960    // 64*512 f32
#define H0BF_OFF  73728    // 64*512 bf16
#define GI_OFF    90112    // 64*1536 f32
#define GH_OFF    188416   // 64*1536 f32
#define STBF_OFF  286720   // 64*512 bf16
#define WCBF_OFF  303104   // 512*1024 bf16
#define SC_OFF    565248   // 2*12800 f32 (n-half partials)
#define REDG_OFF  590848   // 64*391*2 f32
#define RED_OFF   690944   // 64*2 f32

// d_out layout (floats)
#define OUT_STATE 3200000
#define OUT_W     3232768

typedef __attribute__((ext_vector_type(8))) short bf16x8;
typedef __attribute__((ext_vector_type(4))) float f32x4;

__device__ __forceinline__ float sigmf(float x) { return 1.f / (1.f + __expf(-x)); }

__device__ __forceinline__ ushort f2bf(float f) {
  uint u = __float_as_uint(f);
  uint r = (u + 0x7FFFu + ((u >> 16) & 1u)) >> 16;
  return (ushort)r;
}

__device__ __forceinline__ float tanhfast(float x) {
  float xc = fminf(15.f, fmaxf(-15.f, x));
  float e = __expf(2.f * xc);
  return (e - 1.f) * __builtin_amdgcn_rcpf(e + 1.f);
}

// packed f32->bf16 (RNE)
__device__ __forceinline__ bf16x8 cvt8(float4 a, float4 b) {
  union { bf16x8 v; uint u[4]; } r;
  asm("v_cvt_pk_bf16_f32 %0, %1, %2" : "=v"(r.u[0]) : "v"(a.x), "v"(a.y));
  asm("v_cvt_pk_bf16_f32 %0, %1, %2" : "=v"(r.u[1]) : "v"(a.z), "v"(a.w));
  asm("v_cvt_pk_bf16_f32 %0, %1, %2" : "=v"(r.u[2]) : "v"(b.x), "v"(b.y));
  asm("v_cvt_pk_bf16_f32 %0, %1, %2" : "=v"(r.u[3]) : "v"(b.z), "v"(b.w));
  return r.v;
}

// async global->LDS, 16B per lane: lds dest = wave-uniform base + lane*16,
// global src = per-lane address (encodes the layout).
__device__ __forceinline__ void gload16(const void* g, void* l) {
  __builtin_amdgcn_global_load_lds(
      (__attribute__((address_space(1))) void*)(g),
      (__attribute__((address_space(3))) void*)(l), 16, 0, 0);
}

// ---------------- kprep: Wc f32->bf16 (blocks 0..511) + build x_bf/h0 (blocks 512..575)
__global__ void kprep(const float* __restrict__ Wc_W, ushort* __restrict__ Wc_bf,
                      const int* __restrict__ input_idx, const float* __restrict__ encoded,
                      const float* __restrict__ prev_state, const float* __restrict__ weighted,
                      const int* __restrict__ order_p, const float* __restrict__ embed_W,
                      const float* __restrict__ Ws_W, const float* __restrict__ Ws_b,
                      ushort* __restrict__ x_bf, float* __restrict__ h0,
                      ushort* __restrict__ h0_bf) {
  int bid = blockIdx.x, tid = threadIdx.x;
  if (bid < 512) {
    int i = bid * 256 + tid;
    float4 v = ((const float4*)Wc_W)[i];
    ushort4 o;
    o.x = f2bf(v.x); o.y = f2bf(v.y); o.z = f2bf(v.z); o.w = f2bf(v.w);
    ((ushort4*)Wc_bf)[i] = o;
    return;
  }
  int b = bid - 512;
  int order = order_p[0];
  int idx = input_idx[b];
  x_bf[b * KX + tid] = f2bf(embed_W[(size_t)idx * E_DIM + tid]);
  if (order != 0) {
    for (int j = tid; j < H2; j += 256) x_bf[b * KX + E_DIM + j] = f2bf(weighted[b * H2 + j]);
    for (int j = tid; j < H_DIM; j += 256) {
      float v = prev_state[b * H_DIM + j];
      h0[b * H_DIM + j] = v;
      h0_bf[b * H_DIM + j] = f2bf(v);
    }
  } else {
    for (int j = tid; j < H2; j += 256) x_bf[b * KX + E_DIM + j] = 0;
    const float* er = encoded + ((size_t)b * SEQ + 1) * H2;
    for (int j = tid; j < H_DIM; j += 256) {
      float acc = Ws_b[j];
      const float* wr = Ws_W + (size_t)j * H2;
      for (int k = 0; k < H2; ++k) acc = fmaf(er[k], wr[k], acc);
      h0[b * H_DIM + j] = acc;
      h0_bf[b * H_DIM + j] = f2bf(acc);
    }
  }
}

// ---------------- gates GEMM (small): out[m][n] = A[m][:] . W[n][:] + bias[n]
__device__ __forceinline__ void gemm_small(const ushort* __restrict__ Abf,
                                           const float* __restrict__ W,
                                           const float* __restrict__ bias,
                                           float* __restrict__ out, int N, int kdim,
                                           int bid) {
  int tid = threadIdx.x;
  int lane = tid & 63, wv = tid >> 6;
  int l15 = lane & 15, lg = lane >> 4;
  int n0 = (bid * 4 + wv) * 16;
  int col = n0 + l15;
  bool valid = col < N;
  int colc = valid ? col : N - 1;
  f32x4 acc[4];
#pragma unroll
  for (int mt = 0; mt < 4; ++mt) acc[mt] = (f32x4){0.f, 0.f, 0.f, 0.f};
  const float* wrow = W + (size_t)colc * kdim + lg * 8;
  const ushort* arow = Abf + (size_t)l15 * kdim + lg * 8;
#pragma unroll 4
  for (int k0 = 0; k0 < kdim; k0 += 32) {
    float4 w0 = *(const float4*)(wrow + k0);
    float4 w1 = *(const float4*)(wrow + k0 + 4);
    bf16x8 bf = cvt8(w0, w1);
#pragma unroll
    for (int mt = 0; mt < 4; ++mt) {
      bf16x8 af = *(const bf16x8*)(arow + (size_t)mt * 16 * kdim + k0);
      acc[mt] = __builtin_amdgcn_mfma_f32_16x16x32_bf16(af, bf, acc[mt], 0, 0, 0);
    }
  }
  float bv = bias[colc];
  if (valid) {
#pragma unroll
    for (int mt = 0; mt < 4; ++mt)
#pragma unroll
      for (int r = 0; r < 4; ++r)
        out[(size_t)(mt * 16 + lg * 4 + r) * N + col] = acc[mt][r] + bv;
  }
}

__global__ __launch_bounds__(256) void mfma_gates(const ushort* __restrict__ x_bf,
                                                  const float* __restrict__ Wih,
                                                  const float* __restrict__ bih,
                                                  const ushort* __restrict__ h0_bf,
                                                  const float* __restrict__ Whh,
                                                  const float* __restrict__ bhh,
                                                  float* __restrict__ gi, float* __restrict__ gh) {
  if (blockIdx.y == 0)
    gemm_small(x_bf, Wih, bih, gi, G3, KX, blockIdx.x);
  else
    gemm_small(h0_bf, Whh, bhh, gh, G3, H_DIM, blockIdx.x);
}

// ---------------- K2: GRU cell -> state f32 (d_out) + bf16 (ws)
__global__ void k2_gru(const float* __restrict__ gi, const float* __restrict__ gh,
                       const float* __restrict__ h0, float* __restrict__ state_out,
                       ushort* __restrict__ state_bf) {
  int b = blockIdx.x, j = threadIdx.x;  // block = 512
  float ir = gi[b * G3 + j], iz = gi[b * G3 + H_DIM + j], inn = gi[b * G3 + 2 * H_DIM + j];
  float hr = gh[b * G3 + j], hz = gh[b * G3 + H_DIM + j], hn = gh[b * G3 + 2 * H_DIM + j];
  float r = sigmf(ir + hr);
  float z = sigmf(iz + hz);
  float n = tanhf(inn + r * hn);
  float st = (1.f - z) * n + z * h0[b * H_DIM + j];
  state_out[b * H_DIM + j] = st;
  state_bf[b * H_DIM + j] = f2bf(st);
}

// ---------------- wo_stage: score_g = state @ Wo^T + b, + softmax partials.
// 391 blocks x 128 cols. 4 waves x 32 cols. W (f32, HBM) staged via global_load_lds
// into PER-WAVE-PRIVATE frag-major LDS regions; no barriers in the K-loop — only
// counted s_waitcnt vmcnt(4) (4 next-buffer stagings stay in flight). BK=32, 16 iters.
__global__ __launch_bounds__(256) void wo_stage(const ushort* __restrict__ state_bf,
                                                const float* __restrict__ Wo_W,
                                                const float* __restrict__ Wo_b,
                                                float* __restrict__ out,
                                                float* __restrict__ redg) {
  __shared__ char ldsW[2][16384];
  __shared__ float sm[4][64], ss[4][64];
  int tid = threadIdx.x, lane = tid & 63, wv = tid >> 6;
  int l15 = lane & 15, lg = lane >> 4;
  int bid = blockIdx.x;
  int c0 = bid * 128 + wv * 32;
  int col0 = c0 + l15, col1 = c0 + 16 + l15;
  int cc0 = col0 < V ? col0 : V - 1;
  int cc1 = col1 < V ? col1 : V - 1;
  const float* s0 = Wo_W + (size_t)cc0 * H_DIM + lg * 8;
  const float* s1 = Wo_W + (size_t)cc1 * H_DIM + lg * 8;
  const ushort* aptr = state_bf + (size_t)l15 * H_DIM + lg * 8;

  f32x4 acc[4][2];
#pragma unroll
  for (int mt = 0; mt < 4; ++mt)
#pragma unroll
    for (int nf = 0; nf < 2; ++nf) acc[mt][nf] = (f32x4){0.f, 0.f, 0.f, 0.f};

#define STGW(buf, it) do {                      \
    char* d_ = &ldsW[buf][wv * 4096];           \
    gload16(s0 + (it) * 32,     d_);            \
    gload16(s0 + (it) * 32 + 4, d_ + 1024);     \
    gload16(s1 + (it) * 32,     d_ + 2048);     \
    gload16(s1 + (it) * 32 + 4, d_ + 3072);     \
  } while (0)

  STGW(0, 0);
#pragma unroll 1
  for (int it = 0; it < 16; ++it) {
    int cur = it & 1;
    if (it < 15) {
      STGW(cur ^ 1, it + 1);
      asm volatile("s_waitcnt vmcnt(4)" ::: "memory");
    } else {
      asm volatile("s_waitcnt vmcnt(0)" ::: "memory");
    }
    const char* base = &ldsW[cur][wv * 4096];
    float4 w00 = *(const float4*)(base + lane * 16);
    float4 w01 = *(const float4*)(base + 1024 + lane * 16);
    float4 w10 = *(const float4*)(base + 2048 + lane * 16);
    float4 w11 = *(const float4*)(base + 3072 + lane * 16);
    bf16x8 wf0 = cvt8(w00, w01);
    bf16x8 wf1 = cvt8(w10, w11);
#pragma unroll
    for (int mt = 0; mt < 4; ++mt) {
      bf16x8 af = *(const bf16x8*)(aptr + (size_t)mt * 16 * H_DIM + it * 32);
      acc[mt][0] = __builtin_amdgcn_mfma_f32_16x16x32_bf16(af, wf0, acc[mt][0], 0, 0, 0);
      acc[mt][1] = __builtin_amdgcn_mfma_f32_16x16x32_bf16(af, wf1, acc[mt][1], 0, 0, 0);
    }
  }
#undef STGW

  float bv0 = Wo_b[cc0], bv1 = Wo_b[cc1];
  bool v0ok = col0 < V, v1ok = col1 < V;
#pragma unroll
  for (int mt = 0; mt < 4; ++mt)
#pragma unroll
    for (int r = 0; r < 4; ++r) {
      size_t row = (size_t)(mt * 16 + lg * 4 + r) * V;
      if (v0ok) out[row + col0] = acc[mt][0][r] + bv0;
      if (v1ok) out[row + col1] = acc[mt][1][r] + bv1;
    }
  // per-block online (max,sumexp) partials over this block's 128 cols
#pragma unroll
  for (int mt = 0; mt < 4; ++mt)
#pragma unroll
    for (int r = 0; r < 4; ++r) {
      float a0 = v0ok ? acc[mt][0][r] + bv0 : -1e30f;
      float a1 = v1ok ? acc[mt][1][r] + bv1 : -1e30f;
      float mx = fmaxf(a0, a1);
#pragma unroll
      for (int off = 1; off < 16; off <<= 1) mx = fmaxf(mx, __shfl_xor(mx, off, 64));
      float e = (v0ok ? __expf(a0 - mx) : 0.f) + (v1ok ? __expf(a1 - mx) : 0.f);
#pragma unroll
      for (int off = 1; off < 16; off <<= 1) e += __shfl_xor(e, off, 64);
      if (l15 == 0) {
        sm[wv][mt * 16 + lg * 4 + r] = mx;
        ss[wv][mt * 16 + lg * 4 + r] = e;
      }
    }
  __syncthreads();
  if (tid < 64) {
    float M = -1e30f, S = 0.f;
#pragma unroll
    for (int w = 0; w < 4; ++w) {
      float m2 = sm[w][tid], s2 = ss[w][tid];
      float mn = fmaxf(M, m2);
      S = S * __expf(M - mn) + s2 * __expf(m2 - mn);
      M = mn;
    }
    redg[((size_t)tid * NBLK_WO + bid) * 2] = M;
    redg[((size_t)tid * NBLK_WO + bid) * 2 + 1] = S;
  }
}

// ---------------- K4 v6: score_c partials via global_load_lds-staged A.
// 400 blocks = 200 m-tiles x 2 n-halves; 4 waves; wave = all 4 m-frags x 4 n-frags.
// A (encoded f32) staged frag-major (lane-linear => 0 bank conflicts), dbuf,
// 1 barrier/iter. B (Wc_bf) direct per-lane 16B from L2. f32->bf16 at frag load.
__global__ __launch_bounds__(256) void k4_mfma6(const float* __restrict__ encoded,
                                                const ushort* __restrict__ Wc_bf,
                                                const float* __restrict__ Wc_b,
                                                const float* __restrict__ state,
                                                float* __restrict__ scpart) {
  __shared__ char ldsA[2][16384];
  __shared__ float sred[4][64];
  int tid = threadIdx.x, lane = tid & 63, wv = tid >> 6;
  int l15 = lane & 15, lg = lane >> 4;
  int bid = blockIdx.x;
  int mtile = bid >> 1, nhalf = bid & 1;
  int m0 = mtile * 64;
  int nbase = nhalf * 256 + wv * 64;
  // staging: wave w stages rows m0+w*16..+16, both khalves of BK=64
  const float* sbase = encoded + (size_t)(m0 + wv * 16 + l15) * H2 + lg * 8;
  const ushort* bptr = Wc_bf + (size_t)(nbase + l15) * H2 + lg * 8;

  f32x4 acc[4][4];
#pragma unroll
  for (int mt = 0; mt < 4; ++mt)
#pragma unroll
    for (int nf = 0; nf < 4; ++nf) acc[mt][nf] = (f32x4){0.f, 0.f, 0.f, 0.f};

#define STG(buf, it) do {                       \
    const float* s_ = sbase + (it) * 64;        \
    char* d_ = &ldsA[buf][wv * 4096];           \
    gload16(s_,      d_);                       \
    gload16(s_ + 4,  d_ + 1024);                \
    gload16(s_ + 32, d_ + 2048);                \
    gload16(s_ + 36, d_ + 3072);                \
  } while (0)

  STG(0, 0);
#pragma unroll 1
  for (int it = 0; it < 16; ++it) {
    int cur = it & 1;
    __syncthreads();  // drains vmcnt: buffer `cur` staged & visible
    if (it < 15) STG(cur ^ 1, it + 1);
    const char* base = ldsA[cur];
#pragma unroll
    for (int khalf = 0; khalf < 2; ++khalf) {
      bf16x8 af[4];
#pragma unroll
      for (int mt = 0; mt < 4; ++mt) {
        float4 a0 = *(const float4*)(base + mt * 4096 + khalf * 2048 + lane * 16);
        float4 a1 = *(const float4*)(base + mt * 4096 + khalf * 2048 + 1024 + lane * 16);
        af[mt] = cvt8(a0, a1);
      }
#pragma unroll
      for (int nf = 0; nf < 4; ++nf) {
        bf16x8 bf = *(const bf16x8*)(bptr + (size_t)nf * 16 * H2 + it * 64 + khalf * 32);
#pragma unroll
        for (int mt = 0; mt < 4; ++mt)
          acc[mt][nf] = __builtin_amdgcn_mfma_f32_16x16x32_bf16(af[mt], bf, acc[mt][nf], 0, 0, 0);
      }
    }
  }
#undef STG

  // epilogue: tanh(+bias)*state, reduce over this wave's 64 cols, then across waves
  float pv[4][4];
#pragma unroll
  for (int mt = 0; mt < 4; ++mt)
#pragma unroll
    for (int r = 0; r < 4; ++r) pv[mt][r] = 0.f;
#pragma unroll
  for (int nf = 0; nf < 4; ++nf) {
    int n = nbase + nf * 16 + l15;
    float bias = Wc_b[n];
#pragma unroll
    for (int mt = 0; mt < 4; ++mt) {
      int mrow = m0 + mt * 16 + lg * 4;
#pragma unroll
      for (int r = 0; r < 4; ++r) {
        int b = (mrow + r) / SEQ;
        pv[mt][r] += tanhfast(acc[mt][nf][r] + bias) * state[b * H_DIM + n];
      }
    }
  }
#pragma unroll
  for (int off = 1; off < 16; off <<= 1)
#pragma unroll
    for (int mt = 0; mt < 4; ++mt)
#pragma unroll
      for (int r = 0; r < 4; ++r) pv[mt][r] += __shfl_xor(pv[mt][r], off, 64);
  if (l15 == 0) {
#pragma unroll
    for (int mt = 0; mt < 4; ++mt)
#pragma unroll
      for (int r = 0; r < 4; ++r) sred[wv][mt * 16 + lg * 4 + r] = pv[mt][r];
  }
  __syncthreads();
  if (tid < 64) {
    float s = sred[0][tid] + sred[1][tid] + sred[2][tid] + sred[3][tid];
    scpart[(size_t)nhalf * MROWS + m0 + tid] = s;
  }
}

// ---------------- kred: combine redg partials + score_c tail -> red[b] = (max, sum)
__global__ void kred(const float* __restrict__ redg, const float* __restrict__ scpart,
                     const int* __restrict__ eidx, float* __restrict__ red) {
  int b = blockIdx.x, tid = threadIdx.x;
  float m = -1e30f, s = 0.f;
  for (int i = tid; i < NBLK_WO; i += 256) {
    float m2 = redg[((size_t)b * NBLK_WO + i) * 2];
    float s2 = redg[((size_t)b * NBLK_WO + i) * 2 + 1];
    float mn = fmaxf(m, m2);
    s = s * __expf(m - mn) + s2 * __expf(m2 - mn);
    m = mn;
  }
  for (int i = tid; i < SEQ; i += 256) {
    int idx = b * SEQ + i;
    int ei = eidx[idx];
    float scv = scpart[idx] + scpart[MROWS + idx];
    float sc = tanhf(scv + (ei == 0 ? -1000.f : 0.f));
    float mn = fmaxf(m, sc);
    s = s * __expf(m - mn) + __expf(sc - mn);
    m = mn;
  }
  __shared__ float ms[256], ssh[256];
  ms[tid] = m; ssh[tid] = s;
  __syncthreads();
  for (int off = 128; off > 0; off >>= 1) {
    if (tid < off) {
      float m2 = ms[tid + off], s2 = ssh[tid + off];
      float mn = fmaxf(ms[tid], m2);
      ssh[tid] = ssh[tid] * __expf(ms[tid] - mn) + s2 * __expf(m2 - mn);
      ms[tid] = mn;
    }
    __syncthreads();
  }
  if (tid == 0) {
    red[b * 2] = ms[0];
    red[b * 2 + 1] = ssh[0];
  }
}

// ---------------- K7: score_g -> prob_g in place
__global__ void k7_probs(float* __restrict__ sg, const float* __restrict__ red) {
  int i = blockIdx.x * 256 + threadIdx.x;
  int b = i / 12500;
  float mm = red[b * 2], rd = 1.f / red[b * 2 + 1];
  float4* p = (float4*)sg;
  float4 v = p[i];
  v.x = __expf(v.x - mm) * rd;
  v.y = __expf(v.y - mm) * rd;
  v.z = __expf(v.z - mm) * rd;
  v.w = __expf(v.w - mm) * rd;
  p[i] = v;
}

// ---------------- K8: prob_c scatter-add + match-attn weighted sum
__global__ void k8_copy(const float* __restrict__ scpart, const int* __restrict__ eidx,
                        const int* __restrict__ input_idx, const float* __restrict__ red,
                        const float* __restrict__ encoded, float* __restrict__ out,
                        float* __restrict__ wout) {
  int b = blockIdx.x, tid = threadIdx.x;
  __shared__ float att_s[SEQ];
  __shared__ int cnt_s[256];
  float mm = red[b * 2], rd = 1.f / red[b * 2 + 1];
  int inp = input_idx[b];
  int cnt = 0;
  for (int s = tid; s < SEQ; s += 256) {
    int idx = b * SEQ + s;
    int ei = eidx[idx];
    float scv = scpart[idx] + scpart[MROWS + idx];
    float sc = tanhf(scv + (ei == 0 ? -1000.f : 0.f));
    float p = __expf(sc - mm) * rd;
    bool mt = (ei == inp);
    att_s[s] = mt ? p : 0.f;
    cnt += mt ? 1 : 0;
    atomicAdd(&out[(size_t)b * V + ei], p);
  }
  cnt_s[tid] = cnt;
  __syncthreads();
  for (int off = 128; off > 0; off >>= 1) {
    if (tid < off) cnt_s[tid] += cnt_s[tid + off];
    __syncthreads();
  }
  int c = cnt_s[0];
  float scale = (c > 1) ? 1.f / (float)c : 1.f;
  float w0 = 0, w1 = 0, w2 = 0, w3 = 0;
  for (int s = 0; s < SEQ; ++s) {
    float a = att_s[s];
    if (a != 0.f) {
      const float* er = encoded + ((size_t)b * SEQ + s) * H2;
      w0 += a * er[tid];
      w1 += a * er[tid + 256];
      w2 += a * er[tid + 512];
      w3 += a * er[tid + 768];
    }
  }
  wout[b * H2 + tid] = w0 * scale;
  wout[b * H2 + tid + 256] = w1 * scale;
  wout[b * H2 + tid + 512] = w2 * scale;
  wout[b * H2 + tid + 768] = w3 * scale;
}

extern "C" void kernel_launch(void* const* d_in, const int* in_sizes, int n_in,
                              void* d_out, int out_size, void* d_ws, size_t ws_size,
                              hipStream_t stream) {
  const int* input_idx = (const int*)d_in[0];
  const float* encoded = (const float*)d_in[1];
  const int* encoded_idx = (const int*)d_in[2];
  const float* prev_state = (const float*)d_in[3];
  const float* weighted = (const float*)d_in[4];
  const int* order_p = (const int*)d_in[5];
  const float* embed_W = (const float*)d_in[6];
  const float* Wih = (const float*)d_in[7];
  const float* Whh = (const float*)d_in[8];
  const float* bih = (const float*)d_in[9];
  const float* bhh = (const float*)d_in[10];
  const float* Ws_W = (const float*)d_in[11];
  const float* Ws_b = (const float*)d_in[12];
  const float* Wo_W = (const float*)d_in[13];
  const float* Wo_b = (const float*)d_in[14];
  const float* Wc_W = (const float*)d_in[15];
  const float* Wc_b = (const float*)d_in[16];

  float* ws = (float*)d_ws;
  float* out = (float*)d_out;
  ushort* x_bf = (ushort*)(ws + XBF_OFF);
  float* h0 = ws + H0_OFF;
  ushort* h0_bf = (ushort*)(ws + H0BF_OFF);
  float* gi = ws + GI_OFF;
  float* gh = ws + GH_OFF;
  ushort* state_bf = (ushort*)(ws + STBF_OFF);
  ushort* Wc_bf = (ushort*)(ws + WCBF_OFF);
  float* scpart = ws + SC_OFF;
  float* redg = ws + REDG_OFF;
  float* red = ws + RED_OFF;
  float* state = out + OUT_STATE;
  float* wout = out + OUT_W;

  kprep<<<576, 256, 0, stream>>>(Wc_W, Wc_bf, input_idx, encoded, prev_state, weighted,
                                 order_p, embed_W, Ws_W, Ws_b, x_bf, h0, h0_bf);
  mfma_gates<<<dim3(24, 2), 256, 0, stream>>>(x_bf, Wih, bih, h0_bf, Whh, bhh, gi, gh);
  k2_gru<<<64, 512, 0, stream>>>(gi, gh, h0, state, state_bf);
  wo_stage<<<NBLK_WO, 256, 0, stream>>>(state_bf, Wo_W, Wo_b, out, redg);
  k4_mfma6<<<400, 256, 0, stream>>>(encoded, Wc_bf, Wc_b, state, scpart);
  kred<<<64, 256, 0, stream>>>(redg, scpart, encoded_idx, red);
  k7_probs<<<3125, 256, 0, stream>>>(out, red);
  k8_copy<<<64, 256, 0, stream>>>(scpart, encoded_idx, input_idx, red, encoded, out, wout);
}